// Round 18
// baseline (379.222 us; speedup 1.0000x reference)
//
#include <hip/hip_runtime.h>
#include <math.h>

typedef __attribute__((ext_vector_type(8))) short short8;
typedef __attribute__((ext_vector_type(4))) float f32x4;
typedef _Float16 half8 __attribute__((ext_vector_type(8)));
typedef __fp16 fp16x2 __attribute__((ext_vector_type(2)));
typedef unsigned int uint;

__device__ inline uint f2bf(float f) {            // RNE float->bf16 (low 16 bits)
    uint u = __float_as_uint(f);
    return (u + 0x7fffu + ((u >> 16) & 1u)) >> 16;
}
__device__ inline uint pack2(float lo, float hi) { return f2bf(lo) | (f2bf(hi) << 16); }
__device__ inline float bflo(uint u) { return __uint_as_float(u << 16); }
__device__ inline float bfhi(uint u) { return __uint_as_float(u & 0xffff0000u); }
__device__ inline uint cvtpk(float lo, float hi) {
    uint r;
    asm("v_cvt_pk_bf16_f32 %0, %1, %2" : "=v"(r) : "v"(lo), "v"(hi));
    return r;
}
__device__ inline uint pkh(float lo, float hi) {  // 2xf32 -> packed f16 (RTZ)
    union { fp16x2 h; uint u; } c;
    c.h = __builtin_amdgcn_cvt_pkrtz(lo, hi);
    return c.u;
}

// ---------------- fused prep: degree histogram + W1 fp16 frags + W2 bf16 frags ----------------
// blocks [0, nbE): degree; [nbE, nbE+32): w1prep; [nbE+32, nbE+40): w2prep
__global__ void k_prep(const int* __restrict__ dst, int E, int nbE, int* __restrict__ cnt,
                       const float* __restrict__ W1, ushort* __restrict__ w1frag,
                       const float* __restrict__ W2, const float* __restrict__ b2,
                       ushort* __restrict__ w2frag, float* __restrict__ b2pad) {
    int bid = blockIdx.x;
    if (bid < nbE) {
        int i = bid * 256 + threadIdx.x;
        if (i < E) atomicAdd(&cnt[dst[i]], 1);
        return;
    }
    bid -= nbE;
    if (bid < 32) {
        int tid = bid * 256 + threadIdx.x;   // 0..8191
        int ks = tid >> 9;
        int t = (tid >> 6) & 7;
        int l = tid & 63;
        int kbase = ks * 32 + (l >> 4) * 8;
        int c = t * 16 + (l & 15);
#pragma unroll
        for (int j = 0; j < 8; j++) {
            float v = W1[(size_t)(kbase + j) * 128 + c];
            union { _Float16 h; ushort u; } cv;
            cv.h = (_Float16)v;   // RNE
            w1frag[(size_t)tid * 8 + j] = cv.u;
        }
        return;
    }
    bid -= 32;
    {
        int tid = bid * 256 + threadIdx.x;   // 0..2047
        if (tid < 1792) {
            int q = tid / 448;
            int t = (tid >> 6) % 7;
            int l = tid & 63;
            int kbase = q * 32 + (l >> 4) * 8;
            int c = t * 16 + (l & 15);
#pragma unroll
            for (int j = 0; j < 8; j++) {
                float v = (c < 100) ? W2[(kbase + j) * 100 + c] : 0.f;
                w2frag[(size_t)tid * 8 + j] = (ushort)f2bf(v);
            }
        } else if (tid < 1792 + 112) {
            int c = tid - 1792;
            b2pad[c] = (c < 100) ? b2[c] : -1e30f;
        }
    }
}

// ---------------- scan for CSR row_ptr (+ dinv folded in) ----------------
__global__ __launch_bounds__(512) void k_scan1(const int* __restrict__ cnt, int* __restrict__ rp,
                                               int* __restrict__ partials, float* __restrict__ dinv,
                                               int N) {
    __shared__ int s[512];
    int i = blockIdx.x * 512 + threadIdx.x;
    int v = (i < N) ? cnt[i] : 0;
    if (i < N) dinv[i] = rsqrtf((float)(v + 1));   // +1 self loop
    s[threadIdx.x] = v;
    __syncthreads();
    for (int d = 1; d < 512; d <<= 1) {
        int t = (threadIdx.x >= d) ? s[threadIdx.x - d] : 0;
        __syncthreads();
        s[threadIdx.x] += t;
        __syncthreads();
    }
    if (i < N) rp[i] = s[threadIdx.x] - v;
    if (threadIdx.x == 511) partials[blockIdx.x] = s[511];
}

// scan2+scan3 fused: each block sums preceding tile totals itself, then adds offset.
__global__ __launch_bounds__(512) void k_scan3(int* __restrict__ rp, const int* __restrict__ partials,
                                               int N, int E) {
    __shared__ int sw[8];
    int bid = blockIdx.x, tid = threadIdx.x;
    int acc = 0;
    for (int i = tid; i < bid; i += 512) acc += partials[i];
#pragma unroll
    for (int d = 32; d > 0; d >>= 1) acc += __shfl_xor(acc, d, 64);
    if ((tid & 63) == 0) sw[tid >> 6] = acc;
    __syncthreads();
    int tot = 0;
#pragma unroll
    for (int w = 0; w < 8; w++) tot += sw[w];
    int i = bid * 512 + tid;
    if (i < N) rp[i] += tot;
    if (i == 0) rp[N] = E;
}

// edge record: (src as float-bits, dinv[src])
__global__ void k_fill(const int* __restrict__ src, const int* __restrict__ dst, int E,
                       const int* __restrict__ rp, int* __restrict__ cursor,
                       const float* __restrict__ dinv, float2* __restrict__ colw) {
    int i = blockIdx.x * 256 + threadIdx.x;
    if (i < E) {
        int d = dst[i];
        int s = src[i];
        int pos = rp[d] + atomicAdd(&cursor[d], 1);
        colw[pos] = make_float2(__int_as_float(s), dinv[s]);
    }
}

// ---------------- GEMM1 v6 (MFMA fp16, barrier-free main loop): h1 = bf16(x @ W1) ----------------
// 64 rows/block, 8 waves (4 row-quarters x 2 col-halves). Whole x-block (64 rows x K=512)
// resident in LDS as swizzled fp16 (64KB, staged once from a contiguous 128KB read).
// B-fragments stream per-wave straight from L2 (w1f is 128KB, L2-resident) with depth-1
// prefetch — NO barriers and NO vmcnt-drain in the 16-step k-loop.
__global__ __launch_bounds__(512) void k_gemm1(const float* __restrict__ x,
                                               const uint4* __restrict__ w1f,
                                               uint* __restrict__ h1, int N) {
    __shared__ __align__(16) char lds[65536];   // x-tile: 64 rows x 1KB (512 fp16), swizzled
    int tid = threadIdx.x, wv = tid >> 6, l = tid & 63;
    int cl = l & 15, kg = l >> 4;
    int row0 = blockIdx.x * 64;
    int rq = wv & 3, chalf = wv >> 2;

    // ---- stage x: 64 rows x 512 f32 = 128KB contiguous, perfectly coalesced ----
    float4 xa[16];
#pragma unroll
    for (int p = 0; p < 16; p++) {
        int g4 = p * 512 + tid;            // float4 index 0..8191
        int r = g4 >> 7;
        int rg = row0 + r; if (rg >= N) rg = N - 1;
        xa[p] = *(const float4*)(x + (size_t)rg * 512 + (size_t)(g4 & 127) * 4);
    }
#pragma unroll
    for (int p = 0; p < 16; p++) {
        int g4 = p * 512 + tid;
        int r = g4 >> 7;
        int f = g4 & 127;
        int gran = (f >> 1) ^ (r & 7);     // 16B-granule swizzle within 8-row stripes
        *(uint2*)(lds + (size_t)r * 1024 + gran * 16 + (f & 1) * 8)
            = make_uint2(pkh(xa[p].x, xa[p].y), pkh(xa[p].z, xa[p].w));
    }
    __syncthreads();   // the ONLY pre-epilogue barrier

    f32x4 acc[4];
#pragma unroll
    for (int t = 0; t < 4; t++) acc[t] = (f32x4){0.f, 0.f, 0.f, 0.f};

    union U { uint4 u4; half8 h8; };
    int arow = rq * 16 + cl;
    const char* xrow = lds + (size_t)arow * 1024;
    int sw = arow & 7;

    uint4 bq[4];
#pragma unroll
    for (int tt = 0; tt < 4; tt++) bq[tt] = w1f[(chalf * 4 + tt) * 64 + l];

    for (int ks = 0; ks < 16; ks++) {
        U A;
        A.u4 = *(const uint4*)(xrow + (((ks * 4 + kg) ^ sw) * 16));
        uint4 bn[4];
        if (ks < 15) {
#pragma unroll
            for (int tt = 0; tt < 4; tt++)
                bn[tt] = w1f[((ks + 1) * 8 + chalf * 4 + tt) * 64 + l];
        }
#pragma unroll
        for (int tt = 0; tt < 4; tt++) {
            U B;
            B.u4 = bq[tt];
            acc[tt] = __builtin_amdgcn_mfma_f32_16x16x32_f16(A.h8, B.h8, acc[tt], 0, 0, 0);
        }
        if (ks < 15) {
#pragma unroll
            for (int tt = 0; tt < 4; tt++) bq[tt] = bn[tt];
        }
    }
    __syncthreads();   // all waves done reading x-tile before aliasing the epilogue buffer

    // epilogue: C frag (row = rq*16+kg*4+r, col = chalf*64+tt*16+cl) -> packed bf16 via LDS
    uint* hsp = (uint*)lds + (size_t)wv * (16 * 33);
#pragma unroll
    for (int tt = 0; tt < 4; tt++)
#pragma unroll
        for (int r = 0; r < 4; r++) {
            float mine = acc[tt][r];
            float other = __shfl_xor(mine, 1, 64);
            if ((cl & 1) == 0)
                hsp[(kg * 4 + r) * 33 + tt * 8 + (cl >> 1)] = cvtpk(mine, other);
        }
    // same-wave LDS write->read ordering via lgkmcnt; regions are wave-private
#pragma unroll
    for (int p = 0; p < 8; p++) {
        int it = p * 2 + (l >> 5);
        int gr = row0 + rq * 16 + it;
        if (gr < N) h1[(size_t)gr * 64 + chalf * 32 + (l & 31)] = hsp[it * 33 + (l & 31)];
    }
}

// ---------------- aggregation (r10/r12 unroll-8 version — at gather roofline) ----------------
template <bool RELU_BIAS>
__global__ __launch_bounds__(256) void k_agg(const uint* __restrict__ h, const float* __restrict__ dinv,
                                             const int* __restrict__ rp, const float2* __restrict__ colw,
                                             const float* __restrict__ bias, uint* __restrict__ outb, int N) {
    int wave = threadIdx.x >> 6, lane = threadIdx.x & 63;
    int v = blockIdx.x * 4 + wave;
    if (v >= N) return;
    float dv = dinv[v];
    float wself = dv * dv;
    uint us = h[(size_t)v * 64 + lane];
    float acc0 = bflo(us) * wself;
    float acc1 = bfhi(us) * wself;
    int e0 = rp[v], e1 = rp[v + 1];
    int i = e0;
    for (; i + 8 <= e1; i += 8) {
        float2 q[8];
        uint u[8];
#pragma unroll
        for (int j = 0; j < 8; j++) q[j] = colw[i + j];
#pragma unroll
        for (int j = 0; j < 8; j++) u[j] = h[(size_t)__float_as_int(q[j].x) * 64 + lane];
#pragma unroll
        for (int j = 0; j < 8; j++) {
            float w = q[j].y * dv;
            acc0 = fmaf(bflo(u[j]), w, acc0);
            acc1 = fmaf(bfhi(u[j]), w, acc1);
        }
    }
    if (i + 4 <= e1) {
        float2 q[4];
        uint u[4];
#pragma unroll
        for (int j = 0; j < 4; j++) q[j] = colw[i + j];
#pragma unroll
        for (int j = 0; j < 4; j++) u[j] = h[(size_t)__float_as_int(q[j].x) * 64 + lane];
#pragma unroll
        for (int j = 0; j < 4; j++) {
            float w = q[j].y * dv;
            acc0 = fmaf(bflo(u[j]), w, acc0);
            acc1 = fmaf(bfhi(u[j]), w, acc1);
        }
        i += 4;
    }
    for (; i < e1; i++) {
        float2 q = colw[i];
        uint u = h[(size_t)__float_as_int(q.x) * 64 + lane];
        float w = q.y * dv;
        acc0 = fmaf(bflo(u), w, acc0);
        acc1 = fmaf(bfhi(u), w, acc1);
    }
    if (RELU_BIAS) {
        float2 b = *(const float2*)&bias[2 * lane];
        acc0 = fmaxf(acc0 + b.x, 0.f);
        acc1 = fmaxf(acc1 + b.y, 0.f);
    }
    outb[(size_t)v * 64 + lane] = pack2(acc0, acc1);
}

// ---------------- fused MFMA GEMM2 + log_softmax ----------------
__global__ __launch_bounds__(256) void k_out_mfma(const uint* __restrict__ g2u,
                                                  const uint4* __restrict__ w2fragG,
                                                  const float* __restrict__ b2pad,
                                                  float* __restrict__ out, int N) {
    __shared__ uint4 w2s[1792];
    __shared__ float b2s[112];
    int tid = threadIdx.x;
    for (int i = tid; i < 1792; i += 256) w2s[i] = w2fragG[i];
    if (tid < 112) b2s[tid] = b2pad[tid];
    __syncthreads();

    int w = tid >> 6, l = tid & 63;
    int v0 = blockIdx.x * 128 + w * 32;
    int cl = l & 15, gq = l >> 4;

    f32x4 acc[2][7];
#pragma unroll
    for (int m = 0; m < 2; m++)
#pragma unroll
        for (int t = 0; t < 7; t++) acc[m][t] = (f32x4){0.f, 0.f, 0.f, 0.f};

    union U { uint4 u4; short8 s8; };

#pragma unroll
    for (int q = 0; q < 4; q++) {
        short8 afr[2];
#pragma unroll
        for (int m = 0; m < 2; m++) {
            int rv = v0 + m * 16 + cl;
            if (rv >= N) rv = N - 1;
            U a;
            a.u4 = *(const uint4*)&g2u[(size_t)rv * 64 + q * 16 + gq * 4];
            afr[m] = a.s8;
        }
#pragma unroll
        for (int t = 0; t < 7; t++) {
            U b;
            b.u4 = w2s[(q * 7 + t) * 64 + l];
            acc[0][t] = __builtin_amdgcn_mfma_f32_16x16x32_bf16(afr[0], b.s8, acc[0][t], 0, 0, 0);
            acc[1][t] = __builtin_amdgcn_mfma_f32_16x16x32_bf16(afr[1], b.s8, acc[1][t], 0, 0, 0);
        }
    }

    float bsv[7];
#pragma unroll
    for (int t = 0; t < 7; t++) bsv[t] = b2s[t * 16 + cl];

#pragma unroll
    for (int m = 0; m < 2; m++) {
#pragma unroll
        for (int r = 0; r < 4; r++) {
            int row = v0 + m * 16 + gq * 4 + r;
            float lg[7];
#pragma unroll
            for (int t = 0; t < 7; t++) lg[t] = acc[m][t][r] + bsv[t];
            float mx = lg[0];
#pragma unroll
            for (int t = 1; t < 7; t++) mx = fmaxf(mx, lg[t]);
            mx = fmaxf(mx, __shfl_xor(mx, 1, 64));
            mx = fmaxf(mx, __shfl_xor(mx, 2, 64));
            mx = fmaxf(mx, __shfl_xor(mx, 4, 64));
            mx = fmaxf(mx, __shfl_xor(mx, 8, 64));
            float s = 0.f;
#pragma unroll
            for (int t = 0; t < 7; t++) s += __expf(lg[t] - mx);
            s += __shfl_xor(s, 1, 64);
            s += __shfl_xor(s, 2, 64);
            s += __shfl_xor(s, 4, 64);
            s += __shfl_xor(s, 8, 64);
            float lse = mx + __logf(s);
            if (row < N) {
#pragma unroll
                for (int t = 0; t < 7; t++) {
                    int c = t * 16 + cl;
                    if (c < 100) out[(size_t)row * 100 + c] = lg[t] - lse;
                }
            }
        }
    }
}

extern "C" void kernel_launch(void* const* d_in, const int* in_sizes, int n_in,
                              void* d_out, int out_size, void* d_ws, size_t ws_size,
                              hipStream_t stream) {
    const float* x  = (const float*)d_in[0];
    const int*   ei = (const int*)d_in[1];   // int32 (JAX x64 disabled)
    const float* W1 = (const float*)d_in[2];
    const float* b1 = (const float*)d_in[3];
    const float* W2 = (const float*)d_in[4];
    const float* b2 = (const float*)d_in[5];
    float* out = (float*)d_out;

    int N = in_sizes[0] / 512;
    int E = in_sizes[1] / 2;
    const int* srcI = ei;
    const int* dstI = ei + E;

    char* wsb = (char*)d_ws;
    size_t off = 0;
    auto alloc = [&](size_t bytes) {
        void* p = wsb + off;
        off = (off + bytes + 255) & ~(size_t)255;
        return p;
    };
    int*    cnt      = (int*)alloc((size_t)N * 4);
    int*    cursor   = (int*)alloc((size_t)N * 4);
    float*  dinv     = (float*)alloc((size_t)N * 4);
    int*    rp       = (int*)alloc((size_t)(N + 1) * 4);
    int*    partials = (int*)alloc(1024 * 4);
    ushort* w1f      = (ushort*)alloc(8192 * 8 * 2);   // fp16 frags, 131 KB
    ushort* w2frag   = (ushort*)alloc(1792 * 8 * 2);
    float*  b2pad    = (float*)alloc(112 * 4);
    float2* colw     = (float2*)alloc((size_t)E * 8);
    uint*   h1       = (uint*)alloc((size_t)N * 64 * 4);   // bf16 x128 per row
    uint*   a1       = (uint*)alloc((size_t)N * 64 * 4);
    uint*   g2       = h1;  // h1 dead after agg1; reuse

    // cnt and cursor are adjacent in ws: one memset covers both (dinv overwritten by scan1)
    hipMemsetAsync(cnt, 0, (size_t)2 * (((size_t)N * 4 + 255) & ~(size_t)255), stream);

    int nbE = (E + 255) / 256;
    k_prep<<<nbE + 40, 256, 0, stream>>>(dstI, E, nbE, cnt, W1, w1f, W2, b2, w2frag, b2pad);
    int nb = (N + 511) / 512;
    k_scan1<<<nb, 512, 0, stream>>>(cnt, rp, partials, dinv, N);
    k_scan3<<<nb, 512, 0, stream>>>(rp, partials, N, E);
    k_fill<<<(E + 255) / 256, 256, 0, stream>>>(srcI, dstI, E, rp, cursor, dinv, colw);

    k_gemm1<<<(N + 63) / 64, 512, 0, stream>>>(x, (const uint4*)w1f, h1, N);
    k_agg<true><<<(N + 3) / 4, 256, 0, stream>>>(h1, dinv, rp, colw, b1, a1, N);
    k_agg<false><<<(N + 3) / 4, 256, 0, stream>>>(a1, dinv, rp, colw, nullptr, g2, N);
    k_out_mfma<<<(N + 127) / 128, 256, 0, stream>>>(g2, (const uint4*)w2frag, b2pad, out, N);
}

// Round 19
// 354.692 us; speedup vs baseline: 1.0692x; 1.0692x over previous
//
#include <hip/hip_runtime.h>
#include <math.h>

typedef __attribute__((ext_vector_type(8))) short short8;
typedef __attribute__((ext_vector_type(4))) float f32x4;
typedef _Float16 half8 __attribute__((ext_vector_type(8)));
typedef __fp16 fp16x2 __attribute__((ext_vector_type(2)));
typedef unsigned int uint;

__device__ inline uint f2bf(float f) {            // RNE float->bf16 (low 16 bits)
    uint u = __float_as_uint(f);
    return (u + 0x7fffu + ((u >> 16) & 1u)) >> 16;
}
__device__ inline uint pack2(float lo, float hi) { return f2bf(lo) | (f2bf(hi) << 16); }
__device__ inline float bflo(uint u) { return __uint_as_float(u << 16); }
__device__ inline float bfhi(uint u) { return __uint_as_float(u & 0xffff0000u); }
__device__ inline uint cvtpk(float lo, float hi) {
    uint r;
    asm("v_cvt_pk_bf16_f32 %0, %1, %2" : "=v"(r) : "v"(lo), "v"(hi));
    return r;
}
__device__ inline uint pkh(float lo, float hi) {  // 2xf32 -> packed f16 (RTZ)
    union { fp16x2 h; uint u; } c;
    c.h = __builtin_amdgcn_cvt_pkrtz(lo, hi);
    return c.u;
}
__device__ inline void gload16(const void* g, void* l) {  // async global->LDS, 16B/lane
    __builtin_amdgcn_global_load_lds(
        (const __attribute__((address_space(1))) void*)g,
        (__attribute__((address_space(3))) void*)l, 16, 0, 0);
}

// ---------------- fused prep: degree histogram + W1 fp16 frags + W2 bf16 frags ----------------
// blocks [0, nbE): degree; [nbE, nbE+32): w1prep; [nbE+32, nbE+40): w2prep
__global__ void k_prep(const int* __restrict__ dst, int E, int nbE, int* __restrict__ cnt,
                       const float* __restrict__ W1, ushort* __restrict__ w1frag,
                       const float* __restrict__ W2, const float* __restrict__ b2,
                       ushort* __restrict__ w2frag, float* __restrict__ b2pad) {
    int bid = blockIdx.x;
    if (bid < nbE) {
        int i = bid * 256 + threadIdx.x;
        if (i < E) atomicAdd(&cnt[dst[i]], 1);
        return;
    }
    bid -= nbE;
    if (bid < 32) {
        int tid = bid * 256 + threadIdx.x;   // 0..8191
        int ks = tid >> 9;
        int t = (tid >> 6) & 7;
        int l = tid & 63;
        int kbase = ks * 32 + (l >> 4) * 8;
        int c = t * 16 + (l & 15);
#pragma unroll
        for (int j = 0; j < 8; j++) {
            float v = W1[(size_t)(kbase + j) * 128 + c];
            union { _Float16 h; ushort u; } cv;
            cv.h = (_Float16)v;   // RNE
            w1frag[(size_t)tid * 8 + j] = cv.u;
        }
        return;
    }
    bid -= 32;
    {
        int tid = bid * 256 + threadIdx.x;   // 0..2047
        if (tid < 1792) {
            int q = tid / 448;
            int t = (tid >> 6) % 7;
            int l = tid & 63;
            int kbase = q * 32 + (l >> 4) * 8;
            int c = t * 16 + (l & 15);
#pragma unroll
            for (int j = 0; j < 8; j++) {
                float v = (c < 100) ? W2[(kbase + j) * 100 + c] : 0.f;
                w2frag[(size_t)tid * 8 + j] = (ushort)f2bf(v);
            }
        } else if (tid < 1792 + 112) {
            int c = tid - 1792;
            b2pad[c] = (c < 100) ? b2[c] : -1e30f;
        }
    }
}

// ---------------- scan for CSR row_ptr (+ dinv folded in) ----------------
__global__ __launch_bounds__(512) void k_scan1(const int* __restrict__ cnt, int* __restrict__ rp,
                                               int* __restrict__ partials, float* __restrict__ dinv,
                                               int N) {
    __shared__ int s[512];
    int i = blockIdx.x * 512 + threadIdx.x;
    int v = (i < N) ? cnt[i] : 0;
    if (i < N) dinv[i] = rsqrtf((float)(v + 1));   // +1 self loop
    s[threadIdx.x] = v;
    __syncthreads();
    for (int d = 1; d < 512; d <<= 1) {
        int t = (threadIdx.x >= d) ? s[threadIdx.x - d] : 0;
        __syncthreads();
        s[threadIdx.x] += t;
        __syncthreads();
    }
    if (i < N) rp[i] = s[threadIdx.x] - v;
    if (threadIdx.x == 511) partials[blockIdx.x] = s[511];
}

// scan2+scan3 fused: each block sums preceding tile totals itself, then adds offset.
__global__ __launch_bounds__(512) void k_scan3(int* __restrict__ rp, const int* __restrict__ partials,
                                               int N, int E) {
    __shared__ int sw[8];
    int bid = blockIdx.x, tid = threadIdx.x;
    int acc = 0;
    for (int i = tid; i < bid; i += 512) acc += partials[i];
#pragma unroll
    for (int d = 32; d > 0; d >>= 1) acc += __shfl_xor(acc, d, 64);
    if ((tid & 63) == 0) sw[tid >> 6] = acc;
    __syncthreads();
    int tot = 0;
#pragma unroll
    for (int w = 0; w < 8; w++) tot += sw[w];
    int i = bid * 512 + tid;
    if (i < N) rp[i] += tot;
    if (i == 0) rp[N] = E;
}

// ---------------- merged: GEMM1 v5 (blocks [0,nbG)) + CSR fill (rest) ----------------
// gemm blocks dispatch FIRST so MFMA work starts immediately; fill tail overlaps.
__global__ __launch_bounds__(512) void k_fillgemm1(const int* __restrict__ src, const int* __restrict__ dst,
                                                   int E, int nbG, const int* __restrict__ rp,
                                                   int* __restrict__ cursor, const float* __restrict__ dinv,
                                                   float2* __restrict__ colw,
                                                   const float* __restrict__ x,
                                                   const uint4* __restrict__ w1f,
                                                   uint* __restrict__ h1, int N) {
    __shared__ __align__(16) char lds[49152];   // [0,16K): x dbuf (2x8K); [16K,48K): B dbuf (2x16K)
    if (blockIdx.x >= nbG) {
        // ---- CSR fill with edge records (src, dinv[src]) ----
        int i = (blockIdx.x - nbG) * 512 + threadIdx.x;
        if (i < E) {
            int d = dst[i];
            int s = src[i];
            int pos = rp[d] + atomicAdd(&cursor[d], 1);
            colw[pos] = make_float2(__int_as_float(s), dinv[s]);
        }
        return;
    }
    // ---- GEMM1 v5: 64 rows/block, 8 waves (4 row-quarters x 2 col-halves) ----
    int tid = threadIdx.x, wv = tid >> 6, l = tid & 63;
    int cl = l & 15, kg = l >> 4;
    int row0 = blockIdx.x * 64;
    int rq = wv & 3, chalf = wv >> 2;

    int xr = tid >> 3, xs = tid & 7;           // staging: row 0..63, 16B-slot 0..7
    int xrg = row0 + xr; if (xrg >= N) xrg = N - 1;
    const float* xsrc = x + (size_t)xrg * 512 + xs * 8;

    auto stageB = [&](int c) {
        char* bbase = lds + 16384 + (c & 1) * 16384;
        const char* bsrc = (const char*)w1f + (size_t)c * 16384;
#pragma unroll
        for (int i = 0; i < 2; i++) {
            int s = i * 512 + tid;   // granule 0..1023
            gload16(bsrc + (size_t)s * 16, bbase + (size_t)(s - l) * 16);
        }
    };

    float4 f0, f1;
    auto loadx = [&](int c) {
        const float* p = xsrc + c * 64;
        f0 = *(const float4*)p;
        f1 = *(const float4*)(p + 4);
    };
    auto writex = [&](int c) {
        char* xb = lds + (c & 1) * 8192;
        uint4 v;
        v.x = pkh(f0.x, f0.y);
        v.y = pkh(f0.z, f0.w);
        v.z = pkh(f1.x, f1.y);
        v.w = pkh(f1.z, f1.w);
        *(uint4*)(xb + xr * 128 + ((xs ^ (xr & 7)) * 16)) = v;
    };

    f32x4 acc[4];
#pragma unroll
    for (int t = 0; t < 4; t++) acc[t] = (f32x4){0.f, 0.f, 0.f, 0.f};

    union U { uint4 u4; half8 h8; };
    int arow = rq * 16 + cl;

    loadx(0);
    stageB(0);
    writex(0);
    __syncthreads();

    for (int c = 0; c < 8; c++) {
        if (c < 7) { loadx(c + 1); stageB(c + 1); }
        const char* xb = lds + (c & 1) * 8192;
        const char* bb = lds + 16384 + (c & 1) * 16384;
#pragma unroll
        for (int k2 = 0; k2 < 2; k2++) {
            U A;
            A.u4 = *(const uint4*)(xb + arow * 128 + (((k2 * 4 + kg) ^ (arow & 7)) * 16));
#pragma unroll
            for (int tt = 0; tt < 4; tt++) {
                U B;
                B.u4 = *(const uint4*)(bb + (size_t)(((k2 * 8 + chalf * 4 + tt) * 64 + l)) * 16);
                acc[tt] = __builtin_amdgcn_mfma_f32_16x16x32_f16(A.h8, B.h8, acc[tt], 0, 0, 0);
            }
        }
        if (c < 7) writex(c + 1);
        __syncthreads();
    }

    // epilogue: C frag (row = rq*16+kg*4+r, col = chalf*64+tt*16+cl) -> packed bf16 via LDS
    uint* hsp = (uint*)lds + (size_t)wv * (16 * 33);
#pragma unroll
    for (int tt = 0; tt < 4; tt++)
#pragma unroll
        for (int r = 0; r < 4; r++) {
            float mine = acc[tt][r];
            float other = __shfl_xor(mine, 1, 64);
            if ((cl & 1) == 0)
                hsp[(kg * 4 + r) * 33 + tt * 8 + (cl >> 1)] = cvtpk(mine, other);
        }
#pragma unroll
    for (int p = 0; p < 8; p++) {
        int it = p * 2 + (l >> 5);
        int gr = row0 + rq * 16 + it;
        if (gr < N) h1[(size_t)gr * 64 + chalf * 32 + (l & 31)] = hsp[it * 33 + (l & 31)];
    }
}

// ---------------- aggregation (r10/r12 unroll-8 version — at gather roofline) ----------------
template <bool RELU_BIAS>
__global__ __launch_bounds__(256) void k_agg(const uint* __restrict__ h, const float* __restrict__ dinv,
                                             const int* __restrict__ rp, const float2* __restrict__ colw,
                                             const float* __restrict__ bias, uint* __restrict__ outb, int N) {
    int wave = threadIdx.x >> 6, lane = threadIdx.x & 63;
    int v = blockIdx.x * 4 + wave;
    if (v >= N) return;
    float dv = dinv[v];
    float wself = dv * dv;
    uint us = h[(size_t)v * 64 + lane];
    float acc0 = bflo(us) * wself;
    float acc1 = bfhi(us) * wself;
    int e0 = rp[v], e1 = rp[v + 1];
    int i = e0;
    for (; i + 8 <= e1; i += 8) {
        float2 q[8];
        uint u[8];
#pragma unroll
        for (int j = 0; j < 8; j++) q[j] = colw[i + j];
#pragma unroll
        for (int j = 0; j < 8; j++) u[j] = h[(size_t)__float_as_int(q[j].x) * 64 + lane];
#pragma unroll
        for (int j = 0; j < 8; j++) {
            float w = q[j].y * dv;
            acc0 = fmaf(bflo(u[j]), w, acc0);
            acc1 = fmaf(bfhi(u[j]), w, acc1);
        }
    }
    if (i + 4 <= e1) {
        float2 q[4];
        uint u[4];
#pragma unroll
        for (int j = 0; j < 4; j++) q[j] = colw[i + j];
#pragma unroll
        for (int j = 0; j < 4; j++) u[j] = h[(size_t)__float_as_int(q[j].x) * 64 + lane];
#pragma unroll
        for (int j = 0; j < 4; j++) {
            float w = q[j].y * dv;
            acc0 = fmaf(bflo(u[j]), w, acc0);
            acc1 = fmaf(bfhi(u[j]), w, acc1);
        }
        i += 4;
    }
    for (; i < e1; i++) {
        float2 q = colw[i];
        uint u = h[(size_t)__float_as_int(q.x) * 64 + lane];
        float w = q.y * dv;
        acc0 = fmaf(bflo(u), w, acc0);
        acc1 = fmaf(bfhi(u), w, acc1);
    }
    if (RELU_BIAS) {
        float2 b = *(const float2*)&bias[2 * lane];
        acc0 = fmaxf(acc0 + b.x, 0.f);
        acc1 = fmaxf(acc1 + b.y, 0.f);
    }
    outb[(size_t)v * 64 + lane] = pack2(acc0, acc1);
}

// ---------------- fused MFMA GEMM2 + log_softmax ----------------
__global__ __launch_bounds__(256) void k_out_mfma(const uint* __restrict__ g2u,
                                                  const uint4* __restrict__ w2fragG,
                                                  const float* __restrict__ b2pad,
                                                  float* __restrict__ out, int N) {
    __shared__ uint4 w2s[1792];
    __shared__ float b2s[112];
    int tid = threadIdx.x;
    for (int i = tid; i < 1792; i += 256) w2s[i] = w2fragG[i];
    if (tid < 112) b2s[tid] = b2pad[tid];
    __syncthreads();

    int w = tid >> 6, l = tid & 63;
    int v0 = blockIdx.x * 128 + w * 32;
    int cl = l & 15, gq = l >> 4;

    f32x4 acc[2][7];
#pragma unroll
    for (int m = 0; m < 2; m++)
#pragma unroll
        for (int t = 0; t < 7; t++) acc[m][t] = (f32x4){0.f, 0.f, 0.f, 0.f};

    union U { uint4 u4; short8 s8; };

#pragma unroll
    for (int q = 0; q < 4; q++) {
        short8 afr[2];
#pragma unroll
        for (int m = 0; m < 2; m++) {
            int rv = v0 + m * 16 + cl;
            if (rv >= N) rv = N - 1;
            U a;
            a.u4 = *(const uint4*)&g2u[(size_t)rv * 64 + q * 16 + gq * 4];
            afr[m] = a.s8;
        }
#pragma unroll
        for (int t = 0; t < 7; t++) {
            U b;
            b.u4 = w2s[(q * 7 + t) * 64 + l];
            acc[0][t] = __builtin_amdgcn_mfma_f32_16x16x32_bf16(afr[0], b.s8, acc[0][t], 0, 0, 0);
            acc[1][t] = __builtin_amdgcn_mfma_f32_16x16x32_bf16(afr[1], b.s8, acc[1][t], 0, 0, 0);
        }
    }

    float bsv[7];
#pragma unroll
    for (int t = 0; t < 7; t++) bsv[t] = b2s[t * 16 + cl];

#pragma unroll
    for (int m = 0; m < 2; m++) {
#pragma unroll
        for (int r = 0; r < 4; r++) {
            int row = v0 + m * 16 + gq * 4 + r;
            float lg[7];
#pragma unroll
            for (int t = 0; t < 7; t++) lg[t] = acc[m][t][r] + bsv[t];
            float mx = lg[0];
#pragma unroll
            for (int t = 1; t < 7; t++) mx = fmaxf(mx, lg[t]);
            mx = fmaxf(mx, __shfl_xor(mx, 1, 64));
            mx = fmaxf(mx, __shfl_xor(mx, 2, 64));
            mx = fmaxf(mx, __shfl_xor(mx, 4, 64));
            mx = fmaxf(mx, __shfl_xor(mx, 8, 64));
            float s = 0.f;
#pragma unroll
            for (int t = 0; t < 7; t++) s += __expf(lg[t] - mx);
            s += __shfl_xor(s, 1, 64);
            s += __shfl_xor(s, 2, 64);
            s += __shfl_xor(s, 4, 64);
            s += __shfl_xor(s, 8, 64);
            float lse = mx + __logf(s);
            if (row < N) {
#pragma unroll
                for (int t = 0; t < 7; t++) {
                    int c = t * 16 + cl;
                    if (c < 100) out[(size_t)row * 100 + c] = lg[t] - lse;
                }
            }
        }
    }
}

extern "C" void kernel_launch(void* const* d_in, const int* in_sizes, int n_in,
                              void* d_out, int out_size, void* d_ws, size_t ws_size,
                              hipStream_t stream) {
    const float* x  = (const float*)d_in[0];
    const int*   ei = (const int*)d_in[1];   // int32 (JAX x64 disabled)
    const float* W1 = (const float*)d_in[2];
    const float* b1 = (const float*)d_in[3];
    const float* W2 = (const float*)d_in[4];
    const float* b2 = (const float*)d_in[5];
    float* out = (float*)d_out;

    int N = in_sizes[0] / 512;
    int E = in_sizes[1] / 2;
    const int* srcI = ei;
    const int* dstI = ei + E;

    char* wsb = (char*)d_ws;
    size_t off = 0;
    auto alloc = [&](size_t bytes) {
        void* p = wsb + off;
        off = (off + bytes + 255) & ~(size_t)255;
        return p;
    };
    int*    cnt      = (int*)alloc((size_t)N * 4);
    int*    cursor   = (int*)alloc((size_t)N * 4);
    float*  dinv     = (float*)alloc((size_t)N * 4);
    int*    rp       = (int*)alloc((size_t)(N + 1) * 4);
    int*    partials = (int*)alloc(1024 * 4);
    ushort* w1f      = (ushort*)alloc(8192 * 8 * 2);   // fp16 frags, 131 KB
    ushort* w2frag   = (ushort*)alloc(1792 * 8 * 2);
    float*  b2pad    = (float*)alloc(112 * 4);
    float2* colw     = (float2*)alloc((size_t)E * 8);
    uint*   h1       = (uint*)alloc((size_t)N * 64 * 4);   // bf16 x128 per row
    uint*   a1       = (uint*)alloc((size_t)N * 64 * 4);
    uint*   g2       = h1;  // h1 dead after agg1; reuse

    // cnt and cursor are adjacent in ws: one memset covers both (dinv overwritten by scan1)
    hipMemsetAsync(cnt, 0, (size_t)2 * (((size_t)N * 4 + 255) & ~(size_t)255), stream);

    int nbE = (E + 255) / 256;
    k_prep<<<nbE + 40, 256, 0, stream>>>(dstI, E, nbE, cnt, W1, w1f, W2, b2, w2frag, b2pad);
    int nb = (N + 511) / 512;
    k_scan1<<<nb, 512, 0, stream>>>(cnt, rp, partials, dinv, N);
    k_scan3<<<nb, 512, 0, stream>>>(rp, partials, N, E);

    int nbF = (E + 511) / 512;
    int nbG = (N + 63) / 64;
    k_fillgemm1<<<nbG + nbF, 512, 0, stream>>>(srcI, dstI, E, nbG, rp, cursor, dinv, colw,
                                               x, (const uint4*)w1f, h1, N);

    k_agg<true><<<(N + 3) / 4, 256, 0, stream>>>(h1, dinv, rp, colw, b1, a1, N);
    k_agg<false><<<(N + 3) / 4, 256, 0, stream>>>(a1, dinv, rp, colw, nullptr, g2, N);
    k_out_mfma<<<(N + 127) / 128, 256, 0, stream>>>(g2, (const uint4*)w2frag, b2pad, out, N);
}

// Round 20
// 351.098 us; speedup vs baseline: 1.0801x; 1.0102x over previous
//
#include <hip/hip_runtime.h>
#include <math.h>

typedef __attribute__((ext_vector_type(8))) short short8;
typedef __attribute__((ext_vector_type(4))) float f32x4;
typedef _Float16 half8 __attribute__((ext_vector_type(8)));
typedef __fp16 fp16x2 __attribute__((ext_vector_type(2)));
typedef unsigned int uint;

__device__ inline uint f2bf(float f) {            // RNE float->bf16 (low 16 bits)
    uint u = __float_as_uint(f);
    return (u + 0x7fffu + ((u >> 16) & 1u)) >> 16;
}
__device__ inline uint pack2(float lo, float hi) { return f2bf(lo) | (f2bf(hi) << 16); }
__device__ inline float bflo(uint u) { return __uint_as_float(u << 16); }
__device__ inline float bfhi(uint u) { return __uint_as_float(u & 0xffff0000u); }
__device__ inline uint cvtpk(float lo, float hi) {
    uint r;
    asm("v_cvt_pk_bf16_f32 %0, %1, %2" : "=v"(r) : "v"(lo), "v"(hi));
    return r;
}
__device__ inline uint pkh(float lo, float hi) {  // 2xf32 -> packed f16 (RTZ)
    union { fp16x2 h; uint u; } c;
    c.h = __builtin_amdgcn_cvt_pkrtz(lo, hi);
    return c.u;
}
__device__ inline void gload16(const void* g, void* l) {  // async global->LDS, 16B/lane
    __builtin_amdgcn_global_load_lds(
        (const __attribute__((address_space(1))) void*)g,
        (__attribute__((address_space(3))) void*)l, 16, 0, 0);
}

// ---------------- fused prep: degree histogram + W1 fp16 frags + W2 bf16 frags ----------------
// blocks [0, nbE): degree; [nbE, nbE+32): w1prep; [nbE+32, nbE+40): w2prep
__global__ void k_prep(const int* __restrict__ dst, int E, int nbE, int* __restrict__ cnt,
                       const float* __restrict__ W1, ushort* __restrict__ w1frag,
                       const float* __restrict__ W2, const float* __restrict__ b2,
                       ushort* __restrict__ w2frag, float* __restrict__ b2pad) {
    int bid = blockIdx.x;
    if (bid < nbE) {
        int i = bid * 256 + threadIdx.x;
        if (i < E) atomicAdd(&cnt[dst[i]], 1);
        return;
    }
    bid -= nbE;
    if (bid < 32) {
        int tid = bid * 256 + threadIdx.x;   // 0..8191
        int ks = tid >> 9;
        int t = (tid >> 6) & 7;
        int l = tid & 63;
        int kbase = ks * 32 + (l >> 4) * 8;
        int c = t * 16 + (l & 15);
#pragma unroll
        for (int j = 0; j < 8; j++) {
            float v = W1[(size_t)(kbase + j) * 128 + c];
            union { _Float16 h; ushort u; } cv;
            cv.h = (_Float16)v;   // RNE
            w1frag[(size_t)tid * 8 + j] = cv.u;
        }
        return;
    }
    bid -= 32;
    {
        int tid = bid * 256 + threadIdx.x;   // 0..2047
        if (tid < 1792) {
            int q = tid / 448;
            int t = (tid >> 6) % 7;
            int l = tid & 63;
            int kbase = q * 32 + (l >> 4) * 8;
            int c = t * 16 + (l & 15);
#pragma unroll
            for (int j = 0; j < 8; j++) {
                float v = (c < 100) ? W2[(kbase + j) * 100 + c] : 0.f;
                w2frag[(size_t)tid * 8 + j] = (ushort)f2bf(v);
            }
        } else if (tid < 1792 + 112) {
            int c = tid - 1792;
            b2pad[c] = (c < 100) ? b2[c] : -1e30f;
        }
    }
}

// ---------------- scan for CSR row_ptr (+ dinv folded in) ----------------
__global__ __launch_bounds__(512) void k_scan1(const int* __restrict__ cnt, int* __restrict__ rp,
                                               int* __restrict__ partials, float* __restrict__ dinv,
                                               int N) {
    __shared__ int s[512];
    int i = blockIdx.x * 512 + threadIdx.x;
    int v = (i < N) ? cnt[i] : 0;
    if (i < N) dinv[i] = rsqrtf((float)(v + 1));   // +1 self loop
    s[threadIdx.x] = v;
    __syncthreads();
    for (int d = 1; d < 512; d <<= 1) {
        int t = (threadIdx.x >= d) ? s[threadIdx.x - d] : 0;
        __syncthreads();
        s[threadIdx.x] += t;
        __syncthreads();
    }
    if (i < N) rp[i] = s[threadIdx.x] - v;
    if (threadIdx.x == 511) partials[blockIdx.x] = s[511];
}

// scan2+scan3 fused: each block sums preceding tile totals itself, then adds offset.
__global__ __launch_bounds__(512) void k_scan3(int* __restrict__ rp, const int* __restrict__ partials,
                                               int N, int E) {
    __shared__ int sw[8];
    int bid = blockIdx.x, tid = threadIdx.x;
    int acc = 0;
    for (int i = tid; i < bid; i += 512) acc += partials[i];
#pragma unroll
    for (int d = 32; d > 0; d >>= 1) acc += __shfl_xor(acc, d, 64);
    if ((tid & 63) == 0) sw[tid >> 6] = acc;
    __syncthreads();
    int tot = 0;
#pragma unroll
    for (int w = 0; w < 8; w++) tot += sw[w];
    int i = bid * 512 + tid;
    if (i < N) rp[i] += tot;
    if (i == 0) rp[N] = E;
}

// ---------------- merged: GEMM1 v7 (blocks [0,nbG)) + CSR fill (rest) ----------------
// v7: counted-vmcnt pipeline. B tri-buffered (staged 2 chunks ahead); raw s_barrier with
// s_waitcnt vmcnt(2) keeps the next-next B-stage in flight ACROSS the barrier.
__global__ __launch_bounds__(512) void k_fillgemm1(const int* __restrict__ src, const int* __restrict__ dst,
                                                   int E, int nbG, const int* __restrict__ rp,
                                                   int* __restrict__ cursor, const float* __restrict__ dinv,
                                                   float2* __restrict__ colw,
                                                   const float* __restrict__ x,
                                                   const uint4* __restrict__ w1f,
                                                   uint* __restrict__ h1, int N) {
    __shared__ __align__(16) char lds[65536];   // [0,16K): x dbuf (2x8K); [16K,64K): B tribuf (3x16K)
    if (blockIdx.x >= nbG) {
        // ---- CSR fill with edge records (src, dinv[src]) ----
        int i = (blockIdx.x - nbG) * 512 + threadIdx.x;
        if (i < E) {
            int d = dst[i];
            int s = src[i];
            int pos = rp[d] + atomicAdd(&cursor[d], 1);
            colw[pos] = make_float2(__int_as_float(s), dinv[s]);
        }
        return;
    }
    int tid = threadIdx.x, wv = tid >> 6, l = tid & 63;
    int cl = l & 15, kg = l >> 4;
    int row0 = blockIdx.x * 64;
    int rq = wv & 3, chalf = wv >> 2;

    int xr = tid >> 3, xs = tid & 7;           // staging: row 0..63, 16B-slot 0..7
    int xrg = row0 + xr; if (xrg >= N) xrg = N - 1;
    const float* xsrc = x + (size_t)xrg * 512 + xs * 8;

    auto stageB = [&](int c, int buf) {
        char* bbase = lds + 16384 + buf * 16384;
        const char* bsrc = (const char*)w1f + (size_t)c * 16384;
#pragma unroll
        for (int i = 0; i < 2; i++) {
            int s = i * 512 + tid;   // granule 0..1023
            gload16(bsrc + (size_t)s * 16, bbase + (size_t)(s - l) * 16);
        }
    };

    float4 f0, f1;
    auto loadx = [&](int c) {
        const float* p = xsrc + c * 64;
        f0 = *(const float4*)p;
        f1 = *(const float4*)(p + 4);
    };
    auto writex = [&](int c) {
        char* xb = lds + (c & 1) * 8192;
        uint4 v;
        v.x = pkh(f0.x, f0.y);
        v.y = pkh(f0.z, f0.w);
        v.z = pkh(f1.x, f1.y);
        v.w = pkh(f1.z, f1.w);
        *(uint4*)(xb + xr * 128 + ((xs ^ (xr & 7)) * 16)) = v;
    };

    f32x4 acc[4];
#pragma unroll
    for (int t = 0; t < 4; t++) acc[t] = (f32x4){0.f, 0.f, 0.f, 0.f};

    union U { uint4 u4; half8 h8; };
    int arow = rq * 16 + cl;

    // prologue: B(0) + B(1) staged; only B(0) drained before the first barrier.
    loadx(0);
    stageB(0, 0);
    writex(0);                 // compiler drains x(0) loads (older than B ops it tracks)
    stageB(1, 1);
    asm volatile("s_waitcnt vmcnt(2) lgkmcnt(0)" ::: "memory");   // B(0) landed; B(1) in flight
    __builtin_amdgcn_sched_barrier(0);
    __builtin_amdgcn_s_barrier();

    int bufc = 0;   // B buffer holding chunk c
    for (int c = 0; c < 8; c++) {
        if (c < 7) loadx(c + 1);                       // oldest in-flight after this point
        if (c < 6) {
            int bnx = bufc + 2; if (bnx >= 3) bnx -= 3;
            stageB(c + 2, bnx);                        // stays in flight across the barrier
        }
        const char* xb = lds + (c & 1) * 8192;
        const char* bb = lds + 16384 + bufc * 16384;
#pragma unroll
        for (int k2 = 0; k2 < 2; k2++) {
            U A;
            A.u4 = *(const uint4*)(xb + arow * 128 + (((k2 * 4 + kg) ^ (arow & 7)) * 16));
#pragma unroll
            for (int tt = 0; tt < 4; tt++) {
                U B;
                B.u4 = *(const uint4*)(bb + (size_t)(((k2 * 8 + chalf * 4 + tt) * 64 + l)) * 16);
                acc[tt] = __builtin_amdgcn_mfma_f32_16x16x32_f16(A.h8, B.h8, acc[tt], 0, 0, 0);
            }
        }
        if (c < 7) {
            writex(c + 1);     // compiler waits x(c+1) only (older than stageB(c+2))
            if (c < 6) asm volatile("s_waitcnt vmcnt(2) lgkmcnt(0)" ::: "memory"); // B(c+1) done
            else       asm volatile("s_waitcnt vmcnt(0) lgkmcnt(0)" ::: "memory"); // last: full drain
            __builtin_amdgcn_sched_barrier(0);
            __builtin_amdgcn_s_barrier();
        }
        bufc = (bufc + 1 == 3) ? 0 : bufc + 1;
    }
    __syncthreads();   // all waves done reading LDS before aliasing the epilogue buffer

    // epilogue: C frag (row = rq*16+kg*4+r, col = chalf*64+tt*16+cl) -> packed bf16 via LDS
    uint* hsp = (uint*)lds + (size_t)wv * (16 * 33);
#pragma unroll
    for (int tt = 0; tt < 4; tt++)
#pragma unroll
        for (int r = 0; r < 4; r++) {
            float mine = acc[tt][r];
            float other = __shfl_xor(mine, 1, 64);
            if ((cl & 1) == 0)
                hsp[(kg * 4 + r) * 33 + tt * 8 + (cl >> 1)] = cvtpk(mine, other);
        }
#pragma unroll
    for (int p = 0; p < 8; p++) {
        int it = p * 2 + (l >> 5);
        int gr = row0 + rq * 16 + it;
        if (gr < N) h1[(size_t)gr * 64 + chalf * 32 + (l & 31)] = hsp[it * 33 + (l & 31)];
    }
}

// ---------------- aggregation (r10/r12 unroll-8 version — at gather roofline) ----------------
template <bool RELU_BIAS>
__global__ __launch_bounds__(256) void k_agg(const uint* __restrict__ h, const float* __restrict__ dinv,
                                             const int* __restrict__ rp, const float2* __restrict__ colw,
                                             const float* __restrict__ bias, uint* __restrict__ outb, int N) {
    int wave = threadIdx.x >> 6, lane = threadIdx.x & 63;
    int v = blockIdx.x * 4 + wave;
    if (v >= N) return;
    float dv = dinv[v];
    float wself = dv * dv;
    uint us = h[(size_t)v * 64 + lane];
    float acc0 = bflo(us) * wself;
    float acc1 = bfhi(us) * wself;
    int e0 = rp[v], e1 = rp[v + 1];
    int i = e0;
    for (; i + 8 <= e1; i += 8) {
        float2 q[8];
        uint u[8];
#pragma unroll
        for (int j = 0; j < 8; j++) q[j] = colw[i + j];
#pragma unroll
        for (int j = 0; j < 8; j++) u[j] = h[(size_t)__float_as_int(q[j].x) * 64 + lane];
#pragma unroll
        for (int j = 0; j < 8; j++) {
            float w = q[j].y * dv;
            acc0 = fmaf(bflo(u[j]), w, acc0);
            acc1 = fmaf(bfhi(u[j]), w, acc1);
        }
    }
    if (i + 4 <= e1) {
        float2 q[4];
        uint u[4];
#pragma unroll
        for (int j = 0; j < 4; j++) q[j] = colw[i + j];
#pragma unroll
        for (int j = 0; j < 4; j++) u[j] = h[(size_t)__float_as_int(q[j].x) * 64 + lane];
#pragma unroll
        for (int j = 0; j < 4; j++) {
            float w = q[j].y * dv;
            acc0 = fmaf(bflo(u[j]), w, acc0);
            acc1 = fmaf(bfhi(u[j]), w, acc1);
        }
        i += 4;
    }
    for (; i < e1; i++) {
        float2 q = colw[i];
        uint u = h[(size_t)__float_as_int(q.x) * 64 + lane];
        float w = q.y * dv;
        acc0 = fmaf(bflo(u), w, acc0);
        acc1 = fmaf(bfhi(u), w, acc1);
    }
    if (RELU_BIAS) {
        float2 b = *(const float2*)&bias[2 * lane];
        acc0 = fmaxf(acc0 + b.x, 0.f);
        acc1 = fmaxf(acc1 + b.y, 0.f);
    }
    outb[(size_t)v * 64 + lane] = pack2(acc0, acc1);
}

// ---------------- fused MFMA GEMM2 + log_softmax ----------------
__global__ __launch_bounds__(256) void k_out_mfma(const uint* __restrict__ g2u,
                                                  const uint4* __restrict__ w2fragG,
                                                  const float* __restrict__ b2pad,
                                                  float* __restrict__ out, int N) {
    __shared__ uint4 w2s[1792];
    __shared__ float b2s[112];
    int tid = threadIdx.x;
    for (int i = tid; i < 1792; i += 256) w2s[i] = w2fragG[i];
    if (tid < 112) b2s[tid] = b2pad[tid];
    __syncthreads();

    int w = tid >> 6, l = tid & 63;
    int v0 = blockIdx.x * 128 + w * 32;
    int cl = l & 15, gq = l >> 4;

    f32x4 acc[2][7];
#pragma unroll
    for (int m = 0; m < 2; m++)
#pragma unroll
        for (int t = 0; t < 7; t++) acc[m][t] = (f32x4){0.f, 0.f, 0.f, 0.f};

    union U { uint4 u4; short8 s8; };

#pragma unroll
    for (int q = 0; q < 4; q++) {
        short8 afr[2];
#pragma unroll
        for (int m = 0; m < 2; m++) {
            int rv = v0 + m * 16 + cl;
            if (rv >= N) rv = N - 1;
            U a;
            a.u4 = *(const uint4*)&g2u[(size_t)rv * 64 + q * 16 + gq * 4];
            afr[m] = a.s8;
        }
#pragma unroll
        for (int t = 0; t < 7; t++) {
            U b;
            b.u4 = w2s[(q * 7 + t) * 64 + l];
            acc[0][t] = __builtin_amdgcn_mfma_f32_16x16x32_bf16(afr[0], b.s8, acc[0][t], 0, 0, 0);
            acc[1][t] = __builtin_amdgcn_mfma_f32_16x16x32_bf16(afr[1], b.s8, acc[1][t], 0, 0, 0);
        }
    }

    float bsv[7];
#pragma unroll
    for (int t = 0; t < 7; t++) bsv[t] = b2s[t * 16 + cl];

#pragma unroll
    for (int m = 0; m < 2; m++) {
#pragma unroll
        for (int r = 0; r < 4; r++) {
            int row = v0 + m * 16 + gq * 4 + r;
            float lg[7];
#pragma unroll
            for (int t = 0; t < 7; t++) lg[t] = acc[m][t][r] + bsv[t];
            float mx = lg[0];
#pragma unroll
            for (int t = 1; t < 7; t++) mx = fmaxf(mx, lg[t]);
            mx = fmaxf(mx, __shfl_xor(mx, 1, 64));
            mx = fmaxf(mx, __shfl_xor(mx, 2, 64));
            mx = fmaxf(mx, __shfl_xor(mx, 4, 64));
            mx = fmaxf(mx, __shfl_xor(mx, 8, 64));
            float s = 0.f;
#pragma unroll
            for (int t = 0; t < 7; t++) s += __expf(lg[t] - mx);
            s += __shfl_xor(s, 1, 64);
            s += __shfl_xor(s, 2, 64);
            s += __shfl_xor(s, 4, 64);
            s += __shfl_xor(s, 8, 64);
            float lse = mx + __logf(s);
            if (row < N) {
#pragma unroll
                for (int t = 0; t < 7; t++) {
                    int c = t * 16 + cl;
                    if (c < 100) out[(size_t)row * 100 + c] = lg[t] - lse;
                }
            }
        }
    }
}

extern "C" void kernel_launch(void* const* d_in, const int* in_sizes, int n_in,
                              void* d_out, int out_size, void* d_ws, size_t ws_size,
                              hipStream_t stream) {
    const float* x  = (const float*)d_in[0];
    const int*   ei = (const int*)d_in[1];   // int32 (JAX x64 disabled)
    const float* W1 = (const float*)d_in[2];
    const float* b1 = (const float*)d_in[3];
    const float* W2 = (const float*)d_in[4];
    const float* b2 = (const float*)d_in[5];
    float* out = (float*)d_out;

    int N = in_sizes[0] / 512;
    int E = in_sizes[1] / 2;
    const int* srcI = ei;
    const int* dstI = ei + E;

    char* wsb = (char*)d_ws;
    size_t off = 0;
    auto alloc = [&](size_t bytes) {
        void* p = wsb + off;
        off = (off + bytes + 255) & ~(size_t)255;
        return p;
    };
    int*    cnt      = (int*)alloc((size_t)N * 4);
    int*    cursor   = (int*)alloc((size_t)N * 4);
    float*  dinv     = (float*)alloc((size_t)N * 4);
    int*    rp       = (int*)alloc((size_t)(N + 1) * 4);
    int*    partials = (int*)alloc(1024 * 4);
    ushort* w1f      = (ushort*)alloc(8192 * 8 * 2);   // fp16 frags, 131 KB
    ushort* w2frag   = (ushort*)alloc(1792 * 8 * 2);
    float*  b2pad    = (float*)alloc(112 * 4);
    float2* colw     = (float2*)alloc((size_t)E * 8);
    uint*   h1       = (uint*)alloc((size_t)N * 64 * 4);   // bf16 x128 per row
    uint*   a1       = (uint*)alloc((size_t)N * 64 * 4);
    uint*   g2       = h1;  // h1 dead after agg1; reuse

    // cnt and cursor are adjacent in ws: one memset covers both (dinv overwritten by scan1)
    hipMemsetAsync(cnt, 0, (size_t)2 * (((size_t)N * 4 + 255) & ~(size_t)255), stream);

    int nbE = (E + 255) / 256;
    k_prep<<<nbE + 40, 256, 0, stream>>>(dstI, E, nbE, cnt, W1, w1f, W2, b2, w2frag, b2pad);
    int nb = (N + 511) / 512;
    k_scan1<<<nb, 512, 0, stream>>>(cnt, rp, partials, dinv, N);
    k_scan3<<<nb, 512, 0, stream>>>(rp, partials, N, E);

    int nbF = (E + 511) / 512;
    int nbG = (N + 63) / 64;
    k_fillgemm1<<<nbG + nbF, 512, 0, stream>>>(srcI, dstI, E, nbG, rp, cursor, dinv, colw,
                                               x, (const uint4*)w1f, h1, N);

    k_agg<true><<<(N + 3) / 4, 256, 0, stream>>>(h1, dinv, rp, colw, b1, a1, N);
    k_agg<false><<<(N + 3) / 4, 256, 0, stream>>>(a1, dinv, rp, colw, nullptr, g2, N);
    k_out_mfma<<<(N + 127) / 128, 256, 0, stream>>>(g2, (const uint4*)w2frag, b2pad, out, N);
}